// Round 15
// baseline (254.902 us; speedup 1.0000x reference)
//
#include <hip/hip_runtime.h>
#include <hip/hip_fp16.h>

#define NN 50000
#define NE 625000
#define D 128
#define SCAN_BLK 1024  // elements per scan1 block
#define NSB ((NN + SCAN_BLK - 1) / SCAN_BLK)  // 49

typedef _Float16 half8 __attribute__((ext_vector_type(8)));
typedef float f32x4 __attribute__((ext_vector_type(4)));
typedef unsigned int u32x4 __attribute__((ext_vector_type(4)));

union H8U4 { _Float16 h[8]; uint4 u; u32x4 v; };

// ---------------- CSR build ----------------

__global__ void zero_kernel(int4* __restrict__ p) {
    int i = blockIdx.x * blockDim.x + threadIdx.x;
    if (i < NN / 4 + 1) p[i] = make_int4(0, 0, 0, 0);
}

// 4 edges per thread, vectorized edge loads. NE % 4 == 0.
__global__ void count_kernel(const int* __restrict__ col, int* __restrict__ counts) {
    int i = blockIdx.x * blockDim.x + threadIdx.x;
    if (i < NE / 4) {
        int4 c = ((const int4*)col)[i];
        atomicAdd(&counts[c.x], 1);
        atomicAdd(&counts[c.y], 1);
        atomicAdd(&counts[c.z], 1);
        atomicAdd(&counts[c.w], 1);
    }
}

// 256 threads x 4 elements = 1024 counts per block; wave-shuffle scan.
__global__ __launch_bounds__(256) void scan1_kernel(const int* __restrict__ counts,
                                                    int* __restrict__ excl,
                                                    int* __restrict__ blocksums) {
    const int b = blockIdx.x, t = threadIdx.x;
    const int base = b * SCAN_BLK + t * 4;
    int v0 = 0, v1 = 0, v2 = 0, v3 = 0;
    if (base + 3 < NN) {
        int4 c = *(const int4*)(counts + base);
        v0 = c.x; v1 = c.y; v2 = c.z; v3 = c.w;
    } else {
        if (base     < NN) v0 = counts[base];
        if (base + 1 < NN) v1 = counts[base + 1];
        if (base + 2 < NN) v2 = counts[base + 2];
        if (base + 3 < NN) v3 = counts[base + 3];
    }
    const int s = v0 + v1 + v2 + v3;
    const int lane = t & 63, wid = t >> 6;
    int inc = s;
    #pragma unroll
    for (int off = 1; off < 64; off <<= 1) {
        int n = __shfl_up(inc, off, 64);
        if (lane >= off) inc += n;
    }
    __shared__ int wsum[4];
    if (lane == 63) wsum[wid] = inc;
    __syncthreads();
    int wbase = 0;
    for (int w = 0; w < wid; w++) wbase += wsum[w];
    const int texcl = wbase + inc - s;
    if (base     < NN) excl[base]     = texcl;
    if (base + 1 < NN) excl[base + 1] = texcl + v0;
    if (base + 2 < NN) excl[base + 2] = texcl + v0 + v1;
    if (base + 3 < NN) excl[base + 3] = texcl + v0 + v1 + v2;
    if (t == 255) blocksums[b] = wbase + inc;
}

__global__ __launch_bounds__(64) void scan2_kernel(const int* __restrict__ blocksums,
                                                   int* __restrict__ blockoff) {
    const int t = threadIdx.x;
    int v = (t < NSB) ? blocksums[t] : 0;
    int inc = v;
    #pragma unroll
    for (int off = 1; off < 64; off <<= 1) {
        int n = __shfl_up(inc, off, 64);
        if (t >= off) inc += n;
    }
    if (t < NSB) blockoff[t] = inc - v;
}

__global__ void scan3_kernel(const int* __restrict__ counts, const int* __restrict__ excl,
                             const int* __restrict__ blockoff, int* __restrict__ offsets,
                             int* __restrict__ cursor, float* __restrict__ dinv) {
    const int i = blockIdx.x * blockDim.x + threadIdx.x;
    if (i < NN) {
        const int o = excl[i] + blockoff[i >> 10];
        offsets[i] = o;
        cursor[i] = o;
        dinv[i] = rsqrtf((float)counts[i] + 1.0f);  // deg includes self-loop
    }
    if (i == 0) offsets[NN] = NE;
}

// Packed 4B edge record: lo16 = src index (NN<65536), hi16 = fp16 weight.
// 4 edges per thread, vectorized edge loads.
__global__ void fill_kernel(const int* __restrict__ row, const int* __restrict__ col,
                            const float* __restrict__ dinv, int* __restrict__ cursor,
                            uint32_t* __restrict__ csr) {
    int i = blockIdx.x * blockDim.x + threadIdx.x;
    if (i < NE / 4) {
        int4 r4 = ((const int4*)row)[i];
        int4 c4 = ((const int4*)col)[i];
        #pragma unroll
        for (int k = 0; k < 4; k++) {
            int r = (k == 0) ? r4.x : (k == 1) ? r4.y : (k == 2) ? r4.z : r4.w;
            int c = (k == 0) ? c4.x : (k == 1) ? c4.y : (k == 2) ? c4.z : c4.w;
            int p = atomicAdd(&cursor[c], 1);
            __half hw = __float2half_rn(dinv[r] * dinv[c]);
            csr[p] = (uint32_t)r | ((uint32_t)*(const unsigned short*)&hw << 16);
        }
    }
}

// ---------------- W pre-pack (all 3 layers, one launch) ----------------

__global__ __launch_bounds__(256) void wpack3_kernel(const float* __restrict__ W1,
                                                     const float* __restrict__ W2,
                                                     const float* __restrict__ W3,
                                                     uint4* __restrict__ wp) {
    const int b = blockIdx.x;  // 0..23
    const float* W = (b < 8) ? W1 : (b < 16) ? W2 : W3;
    uint4* dst = wp + (size_t)(b >> 3) * 2048;
    int t = (b & 7) * 256 + threadIdx.x;  // 0..2047
    int lane = t & 63, entry = t >> 6;
    int ks = entry >> 3, ctg = entry & 7;
    int j = ctg * 16 + (lane & 15);
    int kb = ks * 32 + (lane >> 4) * 8;
    H8U4 u;
    #pragma unroll
    for (int e = 0; e < 8; e++) u.h[e] = (_Float16)W[(kb + e) * 128 + j];
    dst[t] = u.u;
}

// ---------------- MFMA GEMM: Hh(fp16) = A @ W ----------------
// 64 rows x 128 cols per 256-thread block (4 waves; wave w owns cols w*32..).
// mfma_f32_16x16x32_f16, fp32 accumulate; epilogue via padded LDS, NT stores.

template <bool IN_F16>
__global__ __launch_bounds__(256) void gemm_mfma(const void* __restrict__ Ain,
                                                 const uint4* __restrict__ wpack,
                                                 uint32_t* __restrict__ Hh) {
    __shared__ alignas(16) _Float16 Cs[64][152];
    const int t = threadIdx.x;
    const int w = t >> 6, l = t & 63;
    const int row0 = blockIdx.x * 64;
    const int lr = l & 15;
    const int lg = l >> 4;

    int arow[4];
    #pragma unroll
    for (int rt = 0; rt < 4; rt++) {
        int gr = row0 + rt * 16 + lr;
        arow[rt] = (gr < NN) ? gr : NN - 1;
    }

    f32x4 acc[4][2];
    #pragma unroll
    for (int rt = 0; rt < 4; rt++)
        #pragma unroll
        for (int ct = 0; ct < 2; ct++)
            acc[rt][ct] = (f32x4){0.f, 0.f, 0.f, 0.f};

    #pragma unroll
    for (int ks = 0; ks < 4; ks++) {
        const int kbase = ks * 32 + lg * 8;
        half8 af[4];
        if (IN_F16) {
            const uint4* A = (const uint4*)Ain;
            #pragma unroll
            for (int rt = 0; rt < 4; rt++) {
                H8U4 u;
                u.u = A[arow[rt] * 16 + (kbase >> 3)];
                af[rt] = *(half8*)u.h;
            }
        } else {
            const float4* A = (const float4*)Ain;
            #pragma unroll
            for (int rt = 0; rt < 4; rt++) {
                float4 p0 = A[arow[rt] * 32 + (kbase >> 2)];
                float4 p1 = A[arow[rt] * 32 + (kbase >> 2) + 1];
                half8 h;
                h[0] = (_Float16)p0.x; h[1] = (_Float16)p0.y;
                h[2] = (_Float16)p0.z; h[3] = (_Float16)p0.w;
                h[4] = (_Float16)p1.x; h[5] = (_Float16)p1.y;
                h[6] = (_Float16)p1.z; h[7] = (_Float16)p1.w;
                af[rt] = h;
            }
        }
        half8 bf[2];
        #pragma unroll
        for (int ct = 0; ct < 2; ct++) {
            H8U4 u;
            u.u = wpack[(ks * 8 + (w * 2 + ct)) * 64 + l];
            bf[ct] = *(half8*)u.h;
        }
        #pragma unroll
        for (int rt = 0; rt < 4; rt++)
            #pragma unroll
            for (int ct = 0; ct < 2; ct++)
                acc[rt][ct] = __builtin_amdgcn_mfma_f32_16x16x32_f16(
                    af[rt], bf[ct], acc[rt][ct], 0, 0, 0);
    }

    #pragma unroll
    for (int rt = 0; rt < 4; rt++)
        #pragma unroll
        for (int ct = 0; ct < 2; ct++) {
            const int col = w * 32 + ct * 16 + lr;
            #pragma unroll
            for (int r = 0; r < 4; r++)
                Cs[rt * 16 + lg * 4 + r][col] = (_Float16)acc[rt][ct][r];
        }
    __syncthreads();

    #pragma unroll
    for (int i = t; i < 1024; i += 256) {
        const int row = i >> 4, c16 = i & 15;
        if (row0 + row < NN) {
            u32x4 u = *(const u32x4*)&Cs[row][c16 * 8];
            // row stride = 64 uint32 = 16 u32x4; chunk c16 at 16B granularity
            u32x4* dst = (u32x4*)(Hh + (size_t)(row0 + row) * 64 + c16 * 4);
            __builtin_nontemporal_store(u, dst);
        }
    }
}

// ---------------- aggregation ----------------
// One node per wave64, QUAD-SPLIT: 4 groups of 16 lanes each handle one edge;
// lane loads uint4 = 8 fp16 features. 4-deep pipeline: 16 edges in flight
// (4 independent proc4 gathers issued back-to-back). NT loads on the csr
// stream keep hh16 in L2; NT stores on write-once outputs.

static __device__ __forceinline__ void proc4(uint32_t rec, bool valid, int lg,
                                             const uint4* __restrict__ hh4,
                                             float* __restrict__ acc) {
    const int s = (int)(rec & 0xffffu);
    unsigned short wb = (unsigned short)(rec >> 16);
    const float w = valid ? __half2float(*(const __half*)&wb) : 0.0f;
    uint4 v = hh4[(size_t)s * 16 + lg];
    float2 f0 = __half22float2(*(const __half2*)&v.x);
    float2 f1 = __half22float2(*(const __half2*)&v.y);
    float2 f2 = __half22float2(*(const __half2*)&v.z);
    float2 f3 = __half22float2(*(const __half2*)&v.w);
    acc[0] += w * f0.x; acc[1] += w * f0.y;
    acc[2] += w * f1.x; acc[3] += w * f1.y;
    acc[4] += w * f2.x; acc[5] += w * f2.y;
    acc[6] += w * f3.x; acc[7] += w * f3.y;
}

template <bool OUT_F16>
__global__ __launch_bounds__(256) void agg_kernel(const uint4* __restrict__ hh4,
                                                  const int* __restrict__ offsets,
                                                  const uint32_t* __restrict__ csr,
                                                  const float* __restrict__ dinv,
                                                  const float* __restrict__ bias,
                                                  void* __restrict__ out,
                                                  const int relu) {
    const int node = blockIdx.x * 4 + (threadIdx.x >> 6);
    if (node >= NN) return;
    const int l = threadIdx.x & 63;
    const int g = l >> 4;    // edge-slot group 0..3
    const int lg = l & 15;   // lane in group: features lg*8 .. lg*8+7
    const float di = dinv[node];
    const float sw = di * di;
    const int e0 = offsets[node];
    const int e1 = offsets[node + 1];

    float a0[8], a1[8], a2[8], a3[8];
    #pragma unroll
    for (int i = 0; i < 8; i++) { a0[i] = 0.f; a1[i] = 0.f; a2[i] = 0.f; a3[i] = 0.f; }

    if (e0 < e1) {
        const int elast = e1 - 1;
        int eb = e0;
        uint32_t r0 = __builtin_nontemporal_load(csr + min(eb + g, elast));
        uint32_t r1 = __builtin_nontemporal_load(csr + min(eb + 4 + g, elast));
        uint32_t r2 = __builtin_nontemporal_load(csr + min(eb + 8 + g, elast));
        uint32_t r3 = __builtin_nontemporal_load(csr + min(eb + 12 + g, elast));
        while (eb + 16 <= e1) {
            const int nb = eb + 16;
            uint32_t n0 = __builtin_nontemporal_load(csr + min(nb + g, elast));
            uint32_t n1 = __builtin_nontemporal_load(csr + min(nb + 4 + g, elast));
            uint32_t n2 = __builtin_nontemporal_load(csr + min(nb + 8 + g, elast));
            uint32_t n3 = __builtin_nontemporal_load(csr + min(nb + 12 + g, elast));
            proc4(r0, true, lg, hh4, a0);   // full batch: no masking needed
            proc4(r1, true, lg, hh4, a1);
            proc4(r2, true, lg, hh4, a2);
            proc4(r3, true, lg, hh4, a3);
            r0 = n0; r1 = n1; r2 = n2; r3 = n3; eb = nb;
        }
        const int rem = e1 - eb;
        if (rem > 0)  proc4(r0, eb + g < e1, lg, hh4, a0);
        if (rem > 4)  proc4(r1, eb + 4 + g < e1, lg, hh4, a1);
        if (rem > 8)  proc4(r2, eb + 8 + g < e1, lg, hh4, a2);
        if (rem > 12) proc4(r3, eb + 12 + g < e1, lg, hh4, a3);
    }

    float s[8];
    #pragma unroll
    for (int i = 0; i < 8; i++) s[i] = (a0[i] + a1[i]) + (a2[i] + a3[i]);
    #pragma unroll
    for (int i = 0; i < 8; i++) s[i] += __shfl_xor(s[i], 16, 64);
    #pragma unroll
    for (int i = 0; i < 8; i++) s[i] += __shfl_xor(s[i], 32, 64);

    // self term (fp16 copy) + bias
    uint4 sv = hh4[(size_t)node * 16 + lg];
    float2 f0 = __half22float2(*(const __half2*)&sv.x);
    float2 f1 = __half22float2(*(const __half2*)&sv.y);
    float2 f2 = __half22float2(*(const __half2*)&sv.z);
    float2 f3 = __half22float2(*(const __half2*)&sv.w);
    float4 b0 = ((const float4*)bias)[lg * 2];
    float4 b1 = ((const float4*)bias)[lg * 2 + 1];
    s[0] += sw * f0.x + b0.x; s[1] += sw * f0.y + b0.y;
    s[2] += sw * f1.x + b0.z; s[3] += sw * f1.y + b0.w;
    s[4] += sw * f2.x + b1.x; s[5] += sw * f2.y + b1.y;
    s[6] += sw * f3.x + b1.z; s[7] += sw * f3.y + b1.w;
    if (relu) {
        #pragma unroll
        for (int i = 0; i < 8; i++) s[i] = fmaxf(s[i], 0.f);
    }
    if (g == 0) {
        if (OUT_F16) {
            // fp16 row = 256B = 16 x 16B chunks; this thread owns chunk lg
            __half2 p0 = __float22half2_rn(make_float2(s[0], s[1]));
            __half2 p1 = __float22half2_rn(make_float2(s[2], s[3]));
            __half2 p2 = __float22half2_rn(make_float2(s[4], s[5]));
            __half2 p3 = __float22half2_rn(make_float2(s[6], s[7]));
            u32x4 u;
            u.x = *(const uint32_t*)&p0;
            u.y = *(const uint32_t*)&p1;
            u.z = *(const uint32_t*)&p2;
            u.w = *(const uint32_t*)&p3;
            u32x4* dst = (u32x4*)out + (size_t)node * 16 + lg;
            __builtin_nontemporal_store(u, dst);
        } else {
            // fp32 row = 512B = 32 x 16B chunks; this thread owns chunks 2lg,2lg+1
            f32x4 o0 = {s[0], s[1], s[2], s[3]};
            f32x4 o1 = {s[4], s[5], s[6], s[7]};
            f32x4* dst = (f32x4*)out + (size_t)node * 32 + lg * 2;
            __builtin_nontemporal_store(o0, dst);
            __builtin_nontemporal_store(o1, dst + 1);
        }
    }
}

// ---------------- launch ----------------

extern "C" void kernel_launch(void* const* d_in, const int* in_sizes, int n_in,
                              void* d_out, int out_size, void* d_ws, size_t ws_size,
                              hipStream_t stream) {
    (void)in_sizes; (void)n_in; (void)out_size; (void)ws_size;
    const float* x  = (const float*)d_in[0];
    const int*   ei = (const int*)d_in[1];
    const float* W1 = (const float*)d_in[2];
    const float* b1 = (const float*)d_in[3];
    const float* W2 = (const float*)d_in[4];
    const float* b2 = (const float*)d_in[5];
    const float* W3 = (const float*)d_in[6];
    const float* b3 = (const float*)d_in[7];
    const int* row = ei;
    const int* col = ei + NE;
    float* outp = (float*)d_out;

    char* ws = (char*)d_ws;
    size_t off = 0;
    auto walloc = [&](size_t bytes) -> void* {
        void* p = ws + off;
        off = (off + bytes + 255) & ~(size_t)255;
        return p;
    };
    int*      counts   = (int*)walloc(NN * 4 + 16);
    int*      excl     = (int*)walloc(NN * 4);
    int*      blocksums= (int*)walloc(NSB * 4);
    int*      blockoff = (int*)walloc(NSB * 4);
    int*      offsets  = (int*)walloc((NN + 1) * 4);
    int*      cursor   = (int*)walloc(NN * 4);
    float*    dinv     = (float*)walloc(NN * 4);
    uint32_t* csr      = (uint32_t*)walloc((size_t)NE * 4);
    uint32_t* act16    = (uint32_t*)walloc((size_t)NN * D * 2);
    uint32_t* hh16     = (uint32_t*)walloc((size_t)NN * D * 2);
    uint4*    wp       = (uint4*)walloc(3 * 2048 * 16);

    zero_kernel<<<(NN / 4 + 1 + 255) / 256, 256, 0, stream>>>((int4*)counts);
    count_kernel<<<(NE / 4 + 255) / 256, 256, 0, stream>>>(col, counts);
    scan1_kernel<<<NSB, 256, 0, stream>>>(counts, excl, blocksums);
    scan2_kernel<<<1, 64, 0, stream>>>(blocksums, blockoff);
    scan3_kernel<<<(NN + 255) / 256, 256, 0, stream>>>(counts, excl, blockoff,
                                                       offsets, cursor, dinv);
    fill_kernel<<<(NE / 4 + 255) / 256, 256, 0, stream>>>(row, col, dinv, cursor, csr);
    wpack3_kernel<<<24, 256, 0, stream>>>(W1, W2, W3, wp);

    const int gblocks = (NN + 63) / 64;
    const int ablocks = (NN + 3) / 4;
    const uint4* hh4 = (const uint4*)hh16;
    // layer 1
    gemm_mfma<false><<<gblocks, 256, 0, stream>>>(x, wp, hh16);
    agg_kernel<true><<<ablocks, 256, 0, stream>>>(hh4, offsets, csr, dinv, b1, act16, 1);
    // layer 2
    gemm_mfma<true><<<gblocks, 256, 0, stream>>>(act16, wp + 2048, hh16);
    agg_kernel<true><<<ablocks, 256, 0, stream>>>(hh4, offsets, csr, dinv, b2, act16, 1);
    // layer 3 (no relu, fp32 out)
    gemm_mfma<true><<<gblocks, 256, 0, stream>>>(act16, wp + 4096, hh16);
    agg_kernel<false><<<ablocks, 256, 0, stream>>>(hh4, offsets, csr, dinv, b3, outp, 0);
}

// Round 16
// 208.609 us; speedup vs baseline: 1.2219x; 1.2219x over previous
//
#include <hip/hip_runtime.h>
#include <hip/hip_fp16.h>

#define NN 50000
#define NE 625000
#define D 128
#define SCAN_BLK 1024  // elements per scan1 block
#define NSB ((NN + SCAN_BLK - 1) / SCAN_BLK)  // 49

typedef _Float16 half8 __attribute__((ext_vector_type(8)));
typedef float f32x4 __attribute__((ext_vector_type(4)));

union H8U4 { _Float16 h[8]; uint4 u; };

// ---------------- CSR build ----------------

__global__ void zero_kernel(int4* __restrict__ p) {
    int i = blockIdx.x * blockDim.x + threadIdx.x;
    if (i < NN / 4 + 1) p[i] = make_int4(0, 0, 0, 0);
}

// 4 edges per thread, vectorized edge loads. NE % 4 == 0.
__global__ void count_kernel(const int* __restrict__ col, int* __restrict__ counts) {
    int i = blockIdx.x * blockDim.x + threadIdx.x;
    if (i < NE / 4) {
        int4 c = ((const int4*)col)[i];
        atomicAdd(&counts[c.x], 1);
        atomicAdd(&counts[c.y], 1);
        atomicAdd(&counts[c.z], 1);
        atomicAdd(&counts[c.w], 1);
    }
}

// 256 threads x 4 elements = 1024 counts per block; wave-shuffle scan.
__global__ __launch_bounds__(256) void scan1_kernel(const int* __restrict__ counts,
                                                    int* __restrict__ excl,
                                                    int* __restrict__ blocksums) {
    const int b = blockIdx.x, t = threadIdx.x;
    const int base = b * SCAN_BLK + t * 4;
    int v0 = 0, v1 = 0, v2 = 0, v3 = 0;
    if (base + 3 < NN) {
        int4 c = *(const int4*)(counts + base);
        v0 = c.x; v1 = c.y; v2 = c.z; v3 = c.w;
    } else {
        if (base     < NN) v0 = counts[base];
        if (base + 1 < NN) v1 = counts[base + 1];
        if (base + 2 < NN) v2 = counts[base + 2];
        if (base + 3 < NN) v3 = counts[base + 3];
    }
    const int s = v0 + v1 + v2 + v3;
    const int lane = t & 63, wid = t >> 6;
    int inc = s;
    #pragma unroll
    for (int off = 1; off < 64; off <<= 1) {
        int n = __shfl_up(inc, off, 64);
        if (lane >= off) inc += n;
    }
    __shared__ int wsum[4];
    if (lane == 63) wsum[wid] = inc;
    __syncthreads();
    int wbase = 0;
    for (int w = 0; w < wid; w++) wbase += wsum[w];
    const int texcl = wbase + inc - s;
    if (base     < NN) excl[base]     = texcl;
    if (base + 1 < NN) excl[base + 1] = texcl + v0;
    if (base + 2 < NN) excl[base + 2] = texcl + v0 + v1;
    if (base + 3 < NN) excl[base + 3] = texcl + v0 + v1 + v2;
    if (t == 255) blocksums[b] = wbase + inc;
}

__global__ __launch_bounds__(64) void scan2_kernel(const int* __restrict__ blocksums,
                                                   int* __restrict__ blockoff) {
    const int t = threadIdx.x;
    int v = (t < NSB) ? blocksums[t] : 0;
    int inc = v;
    #pragma unroll
    for (int off = 1; off < 64; off <<= 1) {
        int n = __shfl_up(inc, off, 64);
        if (t >= off) inc += n;
    }
    if (t < NSB) blockoff[t] = inc - v;
}

__global__ void scan3_kernel(const int* __restrict__ counts, const int* __restrict__ excl,
                             const int* __restrict__ blockoff, int* __restrict__ offsets,
                             int* __restrict__ cursor, float* __restrict__ dinv) {
    const int i = blockIdx.x * blockDim.x + threadIdx.x;
    if (i < NN) {
        const int o = excl[i] + blockoff[i >> 10];
        offsets[i] = o;
        cursor[i] = o;
        dinv[i] = rsqrtf((float)counts[i] + 1.0f);  // deg includes self-loop
    }
    if (i == 0) offsets[NN] = NE;
}

// Packed 4B edge record: lo16 = src index (NN<65536), hi16 = fp16 weight.
// 4 edges per thread, vectorized edge loads.
__global__ void fill_kernel(const int* __restrict__ row, const int* __restrict__ col,
                            const float* __restrict__ dinv, int* __restrict__ cursor,
                            uint32_t* __restrict__ csr) {
    int i = blockIdx.x * blockDim.x + threadIdx.x;
    if (i < NE / 4) {
        int4 r4 = ((const int4*)row)[i];
        int4 c4 = ((const int4*)col)[i];
        #pragma unroll
        for (int k = 0; k < 4; k++) {
            int r = (k == 0) ? r4.x : (k == 1) ? r4.y : (k == 2) ? r4.z : r4.w;
            int c = (k == 0) ? c4.x : (k == 1) ? c4.y : (k == 2) ? c4.z : c4.w;
            int p = atomicAdd(&cursor[c], 1);
            __half hw = __float2half_rn(dinv[r] * dinv[c]);
            csr[p] = (uint32_t)r | ((uint32_t)*(const unsigned short*)&hw << 16);
        }
    }
}

// ---------------- W pre-pack (all 3 layers, one launch) ----------------

__global__ __launch_bounds__(256) void wpack3_kernel(const float* __restrict__ W1,
                                                     const float* __restrict__ W2,
                                                     const float* __restrict__ W3,
                                                     uint4* __restrict__ wp) {
    const int b = blockIdx.x;  // 0..23
    const float* W = (b < 8) ? W1 : (b < 16) ? W2 : W3;
    uint4* dst = wp + (size_t)(b >> 3) * 2048;
    int t = (b & 7) * 256 + threadIdx.x;  // 0..2047
    int lane = t & 63, entry = t >> 6;
    int ks = entry >> 3, ctg = entry & 7;
    int j = ctg * 16 + (lane & 15);
    int kb = ks * 32 + (lane >> 4) * 8;
    H8U4 u;
    #pragma unroll
    for (int e = 0; e < 8; e++) u.h[e] = (_Float16)W[(kb + e) * 128 + j];
    dst[t] = u.u;
}

// ---------------- MFMA GEMM: Hh(fp16) = A @ W ----------------
// 64 rows x 128 cols per 256-thread block (4 waves; wave w owns cols w*32..).
// mfma_f32_16x16x32_f16, fp32 accumulate; epilogue via padded LDS.

template <bool IN_F16>
__global__ __launch_bounds__(256) void gemm_mfma(const void* __restrict__ Ain,
                                                 const uint4* __restrict__ wpack,
                                                 uint32_t* __restrict__ Hh) {
    __shared__ alignas(16) _Float16 Cs[64][152];
    const int t = threadIdx.x;
    const int w = t >> 6, l = t & 63;
    const int row0 = blockIdx.x * 64;
    const int lr = l & 15;
    const int lg = l >> 4;

    int arow[4];
    #pragma unroll
    for (int rt = 0; rt < 4; rt++) {
        int gr = row0 + rt * 16 + lr;
        arow[rt] = (gr < NN) ? gr : NN - 1;
    }

    f32x4 acc[4][2];
    #pragma unroll
    for (int rt = 0; rt < 4; rt++)
        #pragma unroll
        for (int ct = 0; ct < 2; ct++)
            acc[rt][ct] = (f32x4){0.f, 0.f, 0.f, 0.f};

    #pragma unroll
    for (int ks = 0; ks < 4; ks++) {
        const int kbase = ks * 32 + lg * 8;
        half8 af[4];
        if (IN_F16) {
            const uint4* A = (const uint4*)Ain;
            #pragma unroll
            for (int rt = 0; rt < 4; rt++) {
                H8U4 u;
                u.u = A[arow[rt] * 16 + (kbase >> 3)];
                af[rt] = *(half8*)u.h;
            }
        } else {
            const float4* A = (const float4*)Ain;
            #pragma unroll
            for (int rt = 0; rt < 4; rt++) {
                float4 p0 = A[arow[rt] * 32 + (kbase >> 2)];
                float4 p1 = A[arow[rt] * 32 + (kbase >> 2) + 1];
                half8 h;
                h[0] = (_Float16)p0.x; h[1] = (_Float16)p0.y;
                h[2] = (_Float16)p0.z; h[3] = (_Float16)p0.w;
                h[4] = (_Float16)p1.x; h[5] = (_Float16)p1.y;
                h[6] = (_Float16)p1.z; h[7] = (_Float16)p1.w;
                af[rt] = h;
            }
        }
        half8 bf[2];
        #pragma unroll
        for (int ct = 0; ct < 2; ct++) {
            H8U4 u;
            u.u = wpack[(ks * 8 + (w * 2 + ct)) * 64 + l];
            bf[ct] = *(half8*)u.h;
        }
        #pragma unroll
        for (int rt = 0; rt < 4; rt++)
            #pragma unroll
            for (int ct = 0; ct < 2; ct++)
                acc[rt][ct] = __builtin_amdgcn_mfma_f32_16x16x32_f16(
                    af[rt], bf[ct], acc[rt][ct], 0, 0, 0);
    }

    #pragma unroll
    for (int rt = 0; rt < 4; rt++)
        #pragma unroll
        for (int ct = 0; ct < 2; ct++) {
            const int col = w * 32 + ct * 16 + lr;
            #pragma unroll
            for (int r = 0; r < 4; r++)
                Cs[rt * 16 + lg * 4 + r][col] = (_Float16)acc[rt][ct][r];
        }
    __syncthreads();

    #pragma unroll
    for (int i = t; i < 1024; i += 256) {
        const int row = i >> 4, c16 = i & 15;
        if (row0 + row < NN) {
            uint4 u = *(const uint4*)&Cs[row][c16 * 8];
            *(uint4*)(Hh + (size_t)(row0 + row) * 64 + c16 * 4) = u;
        }
    }
}

// ---------------- aggregation ----------------
// One node per wave64, QUAD-SPLIT: 4 groups of 16 lanes each handle one edge;
// lane loads uint4 = 8 fp16 features (16 lanes cover the 256B row). One gather
// instruction serves FOUR edges. Full batches of 8 run unmasked (no cndmask);
// tail issues the second proc4 only when >4 edges remain.

static __device__ __forceinline__ void proc4(uint32_t rec, bool valid, int lg,
                                             const uint4* __restrict__ hh4,
                                             float* __restrict__ acc) {
    const int s = (int)(rec & 0xffffu);
    unsigned short wb = (unsigned short)(rec >> 16);
    const float w = valid ? __half2float(*(const __half*)&wb) : 0.0f;
    uint4 v = hh4[(size_t)s * 16 + lg];
    float2 f0 = __half22float2(*(const __half2*)&v.x);
    float2 f1 = __half22float2(*(const __half2*)&v.y);
    float2 f2 = __half22float2(*(const __half2*)&v.z);
    float2 f3 = __half22float2(*(const __half2*)&v.w);
    acc[0] += w * f0.x; acc[1] += w * f0.y;
    acc[2] += w * f1.x; acc[3] += w * f1.y;
    acc[4] += w * f2.x; acc[5] += w * f2.y;
    acc[6] += w * f3.x; acc[7] += w * f3.y;
}

template <bool OUT_F16>
__global__ __launch_bounds__(256) void agg_kernel(const uint4* __restrict__ hh4,
                                                  const int* __restrict__ offsets,
                                                  const uint32_t* __restrict__ csr,
                                                  const float* __restrict__ dinv,
                                                  const float* __restrict__ bias,
                                                  void* __restrict__ out,
                                                  const int relu) {
    const int node = blockIdx.x * 4 + (threadIdx.x >> 6);
    if (node >= NN) return;
    const int l = threadIdx.x & 63;
    const int g = l >> 4;    // edge-slot group 0..3
    const int lg = l & 15;   // lane in group: features lg*8 .. lg*8+7
    const float di = dinv[node];
    const float sw = di * di;
    const int e0 = offsets[node];
    const int e1 = offsets[node + 1];

    float a0[8], a1[8];
    #pragma unroll
    for (int i = 0; i < 8; i++) { a0[i] = 0.f; a1[i] = 0.f; }

    if (e0 < e1) {
        const int elast = e1 - 1;
        int eb = e0;
        uint32_t r0 = csr[min(eb + g, elast)];
        uint32_t r1 = csr[min(eb + 4 + g, elast)];
        while (eb + 8 <= e1) {
            const int nb = eb + 8;
            uint32_t n0 = csr[min(nb + g, elast)];
            uint32_t n1 = csr[min(nb + 4 + g, elast)];
            proc4(r0, true, lg, hh4, a0);   // full batch: no masking needed
            proc4(r1, true, lg, hh4, a1);
            r0 = n0; r1 = n1; eb = nb;
        }
        const int rem = e1 - eb;
        if (rem > 0) proc4(r0, eb + g < e1, lg, hh4, a0);
        if (rem > 4) proc4(r1, eb + 4 + g < e1, lg, hh4, a1);
    }

    float s[8];
    #pragma unroll
    for (int i = 0; i < 8; i++) s[i] = a0[i] + a1[i];
    #pragma unroll
    for (int i = 0; i < 8; i++) s[i] += __shfl_xor(s[i], 16, 64);
    #pragma unroll
    for (int i = 0; i < 8; i++) s[i] += __shfl_xor(s[i], 32, 64);

    // self term (fp16 copy) + bias
    uint4 sv = hh4[(size_t)node * 16 + lg];
    float2 f0 = __half22float2(*(const __half2*)&sv.x);
    float2 f1 = __half22float2(*(const __half2*)&sv.y);
    float2 f2 = __half22float2(*(const __half2*)&sv.z);
    float2 f3 = __half22float2(*(const __half2*)&sv.w);
    float4 b0 = ((const float4*)bias)[lg * 2];
    float4 b1 = ((const float4*)bias)[lg * 2 + 1];
    s[0] += sw * f0.x + b0.x; s[1] += sw * f0.y + b0.y;
    s[2] += sw * f1.x + b0.z; s[3] += sw * f1.y + b0.w;
    s[4] += sw * f2.x + b1.x; s[5] += sw * f2.y + b1.y;
    s[6] += sw * f3.x + b1.z; s[7] += sw * f3.y + b1.w;
    if (relu) {
        #pragma unroll
        for (int i = 0; i < 8; i++) s[i] = fmaxf(s[i], 0.f);
    }
    if (g == 0) {
        if (OUT_F16) {
            __half2 p0 = __float22half2_rn(make_float2(s[0], s[1]));
            __half2 p1 = __float22half2_rn(make_float2(s[2], s[3]));
            __half2 p2 = __float22half2_rn(make_float2(s[4], s[5]));
            __half2 p3 = __float22half2_rn(make_float2(s[6], s[7]));
            uint4 u;
            u.x = *(const uint32_t*)&p0;
            u.y = *(const uint32_t*)&p1;
            u.z = *(const uint32_t*)&p2;
            u.w = *(const uint32_t*)&p3;
            ((uint4*)out)[(size_t)node * 16 + lg] = u;
        } else {
            float4 o0 = make_float4(s[0], s[1], s[2], s[3]);
            float4 o1 = make_float4(s[4], s[5], s[6], s[7]);
            ((float4*)out)[(size_t)node * 32 + lg * 2] = o0;
            ((float4*)out)[(size_t)node * 32 + lg * 2 + 1] = o1;
        }
    }
}

// ---------------- launch ----------------

extern "C" void kernel_launch(void* const* d_in, const int* in_sizes, int n_in,
                              void* d_out, int out_size, void* d_ws, size_t ws_size,
                              hipStream_t stream) {
    (void)in_sizes; (void)n_in; (void)out_size; (void)ws_size;
    const float* x  = (const float*)d_in[0];
    const int*   ei = (const int*)d_in[1];
    const float* W1 = (const float*)d_in[2];
    const float* b1 = (const float*)d_in[3];
    const float* W2 = (const float*)d_in[4];
    const float* b2 = (const float*)d_in[5];
    const float* W3 = (const float*)d_in[6];
    const float* b3 = (const float*)d_in[7];
    const int* row = ei;
    const int* col = ei + NE;
    float* outp = (float*)d_out;

    char* ws = (char*)d_ws;
    size_t off = 0;
    auto walloc = [&](size_t bytes) -> void* {
        void* p = ws + off;
        off = (off + bytes + 255) & ~(size_t)255;
        return p;
    };
    int*      counts   = (int*)walloc(NN * 4 + 16);
    int*      excl     = (int*)walloc(NN * 4);
    int*      blocksums= (int*)walloc(NSB * 4);
    int*      blockoff = (int*)walloc(NSB * 4);
    int*      offsets  = (int*)walloc((NN + 1) * 4);
    int*      cursor   = (int*)walloc(NN * 4);
    float*    dinv     = (float*)walloc(NN * 4);
    uint32_t* csr      = (uint32_t*)walloc((size_t)NE * 4);
    uint32_t* act16    = (uint32_t*)walloc((size_t)NN * D * 2);
    uint32_t* hh16     = (uint32_t*)walloc((size_t)NN * D * 2);
    uint4*    wp       = (uint4*)walloc(3 * 2048 * 16);

    zero_kernel<<<(NN / 4 + 1 + 255) / 256, 256, 0, stream>>>((int4*)counts);
    count_kernel<<<(NE / 4 + 255) / 256, 256, 0, stream>>>(col, counts);
    scan1_kernel<<<NSB, 256, 0, stream>>>(counts, excl, blocksums);
    scan2_kernel<<<1, 64, 0, stream>>>(blocksums, blockoff);
    scan3_kernel<<<(NN + 255) / 256, 256, 0, stream>>>(counts, excl, blockoff,
                                                       offsets, cursor, dinv);
    fill_kernel<<<(NE / 4 + 255) / 256, 256, 0, stream>>>(row, col, dinv, cursor, csr);
    wpack3_kernel<<<24, 256, 0, stream>>>(W1, W2, W3, wp);

    const int gblocks = (NN + 63) / 64;
    const int ablocks = (NN + 3) / 4;
    const uint4* hh4 = (const uint4*)hh16;
    // layer 1
    gemm_mfma<false><<<gblocks, 256, 0, stream>>>(x, wp, hh16);
    agg_kernel<true><<<ablocks, 256, 0, stream>>>(hh4, offsets, csr, dinv, b1, act16, 1);
    // layer 2
    gemm_mfma<true><<<gblocks, 256, 0, stream>>>(act16, wp + 2048, hh16);
    agg_kernel<true><<<ablocks, 256, 0, stream>>>(hh4, offsets, csr, dinv, b2, act16, 1);
    // layer 3 (no relu, fp32 out)
    gemm_mfma<true><<<gblocks, 256, 0, stream>>>(act16, wp + 4096, hh16);
    agg_kernel<false><<<ablocks, 256, 0, stream>>>(hh4, offsets, csr, dinv, b3, outp, 0);
}